// Round 1
// baseline (92.616 us; speedup 1.0000x reference)
//
#include <hip/hip_runtime.h>

// VQC: NQ=4 qubits, NL=1 layer, B=1048576.
// Per element: state = ⊗_q RZ(e2)RY(e1)RZ(e0)|+>  (product state, 2 cplx/qubit)
// -> 16 amps via tensor product -> CNOT chain (compile-time permutation)
// -> z_q via U3-fused measurement: z_q = sum_pairs alpha*(p_i-p_j) + g1*Re(a_i conj(a_j)) + g2*Im(...)
// (U3 on other qubits commutes with Z_q; phi drops out of the Z expectation.)

__global__ void vqc_prep(const float* __restrict__ w, float* __restrict__ mz) {
    int q = threadIdx.x;
    if (q >= 4) return;
    float th = w[q * 3 + 0];
    float lm = w[q * 3 + 2];   // phi (w[q*3+1]) provably drops out of <Z_q>
    float s, c, sl, cl;
    sincosf(0.5f * th, &s, &c);
    sincosf(lm, &sl, &cl);
    // U3 = [[c, -e^{i lm} s], [e^{i ph} s, e^{i(ph+lm)} c]]
    // alpha = |W00|^2-|W10|^2 = c^2-s^2  (and |W01|^2-|W11|^2 = -alpha)
    // gamma = W00 conj(W01) - W10 conj(W11) = -2 c s e^{-i lm}
    // contrib = alpha*(p_i - p_j) + 2*gx*Re(aij) - 2*gy*Im(aij)
    mz[q * 4 + 0] = c * c - s * s;
    mz[q * 4 + 1] = -4.0f * c * s * cl;   // g1 = 2*gamma_x
    mz[q * 4 + 2] = -4.0f * c * s * sl;   // g2 = -2*gamma_y
    mz[q * 4 + 3] = 0.0f;
}

__global__ __launch_bounds__(256) void vqc_main(const float4* __restrict__ enc,
                                                const float4* __restrict__ mz,
                                                float4* __restrict__ out, int B) {
    int b = blockIdx.x * blockDim.x + threadIdx.x;
    if (b >= B) return;

    // coalesced: 3x float4 per thread (48B contiguous)
    float4 e0 = enc[b * 3 + 0];
    float4 e1 = enc[b * 3 + 1];
    float4 e2 = enc[b * 3 + 2];
    // uniform-address broadcast loads (L2-resident, 64B total)
    float4 m0 = mz[0], m1 = mz[1], m2 = mz[2], m3 = mz[3];

    float ang[12] = {e0.x, e0.y, e0.z, e0.w, e1.x, e1.y, e1.z, e1.w,
                     e2.x, e2.y, e2.z, e2.w};

    // per-qubit encoded single-qubit state v[q] = RZ(g) RY(b) RZ(a) |+>
    float vx[4][2], vy[4][2];
    const float inv = 0.70710678118654752f;
#pragma unroll
    for (int q = 0; q < 4; ++q) {
        float sa, ca, sb, cb, sg, cg;
        __sincosf(0.5f * ang[3 * q + 0], &sa, &ca);
        __sincosf(0.5f * ang[3 * q + 1], &sb, &cb);
        __sincosf(0.5f * ang[3 * q + 2], &sg, &cg);
        float P = cb - sb, Q = cb + sb;
        float y0x = ca * P * inv, y0y = -sa * Q * inv;
        float y1x = ca * Q * inv, y1y = sa * P * inv;
        vx[q][0] = cg * y0x + sg * y0y;   // e^{-i g/2} * y0
        vy[q][0] = cg * y0y - sg * y0x;
        vx[q][1] = cg * y1x - sg * y1y;   // e^{+i g/2} * y1
        vy[q][1] = cg * y1y + sg * y1x;
    }

    // tensor product: idx = b0*8 + b1*4 + b2*2 + b3 (qubit 0 = MSB, matches
    // row-major flatten of state shape (2,2,2,2))
    float ux[4], uy[4], wx[4], wy[4];
#pragma unroll
    for (int i = 0; i < 2; ++i)
#pragma unroll
        for (int j = 0; j < 2; ++j) {
            ux[i * 2 + j] = vx[0][i] * vx[1][j] - vy[0][i] * vy[1][j];
            uy[i * 2 + j] = vx[0][i] * vy[1][j] + vy[0][i] * vx[1][j];
            wx[i * 2 + j] = vx[2][i] * vx[3][j] - vy[2][i] * vy[3][j];
            wy[i * 2 + j] = vx[2][i] * vy[3][j] + vy[2][i] * vx[3][j];
        }

    float ax[16], ay[16];
#pragma unroll
    for (int h = 0; h < 4; ++h)
#pragma unroll
        for (int l = 0; l < 4; ++l) {
            ax[h * 4 + l] = ux[h] * wx[l] - uy[h] * wy[l];
            ay[h * 4 + l] = ux[h] * wy[l] + uy[h] * wx[l];
        }

    // CNOT chain (0,1),(1,2),(2,3),(3,0): pure register permutation.
    // mask(q) = 8>>q. if bit_c set -> swap the bit_t pair.
    const int cm[4] = {8, 4, 2, 1};
    const int tm[4] = {4, 2, 1, 8};
#pragma unroll
    for (int k = 0; k < 4; ++k) {
#pragma unroll
        for (int i = 0; i < 16; ++i) {
            if ((i & cm[k]) && !(i & tm[k])) {
                int j = i | tm[k];
                float tx = ax[i], ty = ay[i];
                ax[i] = ax[j]; ay[i] = ay[j];
                ax[j] = tx;    ay[j] = ty;
            }
        }
    }

    float p[16];
#pragma unroll
    for (int i = 0; i < 16; ++i) p[i] = ax[i] * ax[i] + ay[i] * ay[i];

    float al[4] = {m0.x, m1.x, m2.x, m3.x};
    float g1[4] = {m0.y, m1.y, m2.y, m3.y};
    float g2[4] = {m0.z, m1.z, m2.z, m3.z};

    float z[4];
#pragma unroll
    for (int q = 0; q < 4; ++q) {
        int m = 8 >> q;
        float acc = 0.0f;
#pragma unroll
        for (int i = 0; i < 16; ++i) {
            if (!(i & m)) {
                int j = i | m;
                float cx = ax[i] * ax[j] + ay[i] * ay[j];
                float cy = ay[i] * ax[j] - ax[i] * ay[j];
                acc += al[q] * (p[i] - p[j]) + g1[q] * cx + g2[q] * cy;
            }
        }
        z[q] = acc;
    }

    out[b] = make_float4(z[0], z[1], z[2], z[3]);
}

extern "C" void kernel_launch(void* const* d_in, const int* in_sizes, int n_in,
                              void* d_out, int out_size, void* d_ws, size_t ws_size,
                              hipStream_t stream) {
    const float* enc = (const float*)d_in[0];   // (B, 4, 3) f32
    const float* w   = (const float*)d_in[1];   // (1, 4, 3) f32
    float* out = (float*)d_out;                 // (B, 4) f32
    float* mz  = (float*)d_ws;                  // 16 f32 scratch

    int B = in_sizes[0] / 12;

    vqc_prep<<<1, 64, 0, stream>>>(w, mz);
    int grid = (B + 255) / 256;
    vqc_main<<<grid, 256, 0, stream>>>((const float4*)enc, (const float4*)mz,
                                       (float4*)out, B);
}